// Round 3
// baseline (111.831 us; speedup 1.0000x reference)
//
#include <hip/hip_runtime.h>

// Haar DWT2D forward: (8,32,512,512) f32 -> (8,128,257,257) f32
// out[b, k*32+c, i, j] = sum_t filt[k,t] * win_t; 2x2 window for output (i,j)
// is input rows {2i-1, 2i}, cols {2j-1, 2j}, reflect-1 (-1 -> 1, 512 -> 510).
//
// One block per (plane, 16-row group). Reg-staged, double-buffered LDS
// pipeline: prefetch row-pair i+1 before the barrier so HBM latency overlaps
// row i's compute+stores. One barrier per row.

constexpr int H_IN  = 512;
constexpr int W_IN  = 512;
constexpr int H_OUT = 257;
constexpr int W_OUT = 257;
constexpr int NROWS = 16;    // output rows per block
constexpr long long PLANE_OUT = (long long)H_OUT * W_OUT;   // 66049
constexpr long long PLANE_IN  = (long long)H_IN * W_IN;     // 262144

__global__ __launch_bounds__(256)
void dwt2d_haar_pipe(const float* __restrict__ x,
                     const float* __restrict__ filt,
                     float* __restrict__ out) {
    const int ib = blockIdx.x * NROWS;   // first output row of this block
    const int bc = blockIdx.y;           // b*32 + c
    const int t  = threadIdx.x;

    __shared__ float buf[2][2][W_IN];    // [dbuf][row-of-pair][col], 8 KiB

    const float* xp   = x + (long long)bc * PLANE_IN;
    const int    half = t >> 7;          // 0: top row of pair, 1: bottom
    const int    lane = (t & 127) << 2;  // col 0,4,...,508

    auto load_pair = [&](int i) -> float4 {
        int r0 = 2 * i - 1; if (r0 < 0)     r0 = 1;          // reflect top
        int r1 = 2 * i;     if (r1 >= H_IN) r1 = H_IN - 2;   // reflect bottom
        const int r = half ? r1 : r0;
        return *reinterpret_cast<const float4*>(xp + r * W_IN + lane);
    };

    float F[16];
#pragma unroll
    for (int k = 0; k < 16; ++k) F[k] = filt[k];

    const int bb = bc >> 5, cc = bc & 31;
    const long long plane_base = (long long)(bb * 128 + cc) * PLANE_OUT;

    const int nvalid = (H_OUT - ib < NROWS) ? (H_OUT - ib) : NROWS;

    float4 v = load_pair(ib);
    int cur = 0;
    for (int it = 0; it < nvalid; ++it) {
        const int i = ib + it;

        // stage current pair to LDS
        float* dst = &buf[cur][half][lane];
        dst[0] = v.x; dst[1] = v.y; dst[2] = v.z; dst[3] = v.w;

        // issue next pair's loads before the barrier (latency overlaps compute)
        if (it + 1 < nvalid) v = load_pair(i + 1);

        __syncthreads();

        const float* r0p = buf[cur][0];
        const float* r1p = buf[cur][1];
        int c0 = 2 * t - 1; if (c0 < 0) c0 = 1;   // reflect left
        int c1 = 2 * t;
        float a = r0p[c0], b = r0p[c1];
        float c = r1p[c0], d = r1p[c1];

        const long long obase = plane_base + (long long)i * W_OUT;
#pragma unroll
        for (int k = 0; k < 4; ++k) {
            float vv = F[4*k+0] * a + F[4*k+1] * b + F[4*k+2] * c + F[4*k+3] * d;
            __builtin_nontemporal_store(vv, &out[obase + (long long)(k * 32) * PLANE_OUT + t]);
        }
        if (t == 0) {   // column tail j = 256 (c0=511, c1=512 -> reflect 510)
            float a2 = r0p[511], b2 = r0p[510];
            float c2 = r1p[511], d2 = r1p[510];
#pragma unroll
            for (int k = 0; k < 4; ++k) {
                float vv = F[4*k+0] * a2 + F[4*k+1] * b2 + F[4*k+2] * c2 + F[4*k+3] * d2;
                __builtin_nontemporal_store(vv, &out[obase + (long long)(k * 32) * PLANE_OUT + 256]);
            }
        }
        cur ^= 1;
        // no second barrier: double buffer + next iteration's mid-barrier
        // orders the next write to this buffer after all reads of it
    }
}

extern "C" void kernel_launch(void* const* d_in, const int* in_sizes, int n_in,
                              void* d_out, int out_size, void* d_ws, size_t ws_size,
                              hipStream_t stream) {
    const float* x    = (const float*)d_in[0];
    const float* filt = (const float*)d_in[1];
    float*       out  = (float*)d_out;

    dim3 grid((H_OUT + NROWS - 1) / NROWS, 256);   // 17 x 256 = 4352 blocks
    dwt2d_haar_pipe<<<grid, 256, 0, stream>>>(x, filt, out);
}

// Round 4
// 100.284 us; speedup vs baseline: 1.1151x; 1.1151x over previous
//
#include <hip/hip_runtime.h>

// Haar DWT2D forward: (8,32,512,512) f32 -> (8,128,257,257) f32
// out[b, k*32+c, i, j0] uses input rows {2i-1, 2i}, cols {2j0-1, 2j0},
// reflect-1 padding (-1 -> 1, 512 -> 510).
//
// Pure-register kernel: no LDS, no barriers. Each thread handles one output
// row and 2 output cols (j0 = 2j, 2j+1): one aligned float4 per input row
// (cols 4j..4j+3); col 4j-1 comes from the left lane via shfl_up, wave-seam
// lanes (1/64) do a predicated scalar load (L1 hit).

constexpr int H_IN  = 512;
constexpr int W_IN  = 512;
constexpr int H_OUT = 257;
constexpr int W_OUT = 257;
constexpr long long PLANE_OUT = (long long)H_OUT * W_OUT;   // 66049
constexpr long long PLANE_IN  = (long long)H_IN * W_IN;     // 262144

typedef float f2v __attribute__((ext_vector_type(2), aligned(4)));

__global__ __launch_bounds__(256)
void dwt2d_haar_reg(const float* __restrict__ x,
                    const float* __restrict__ filt,
                    float* __restrict__ out) {
    const int t  = threadIdx.x;
    const int j  = t & 127;                       // col group within the row
    const int i  = blockIdx.x * 2 + (t >> 7);     // output row
    const int bc = blockIdx.y;                    // b*32 + c
    if (i >= H_OUT) return;

    int r0 = 2 * i - 1; if (r0 < 0)     r0 = 1;          // reflect top
    int r1 = 2 * i;     if (r1 >= H_IN) r1 = H_IN - 2;   // reflect bottom

    const float* xp = x + (long long)bc * PLANE_IN;
    const float4 v0 = *reinterpret_cast<const float4*>(xp + r0 * W_IN + 4 * j);
    const float4 v1 = *reinterpret_cast<const float4*>(xp + r1 * W_IN + 4 * j);

    // col 4j-1: from left lane; lane 0 of each wave handles seam/reflect.
    float p0 = __shfl_up(v0.w, 1);
    float p1 = __shfl_up(v1.w, 1);
    if ((t & 63) == 0) {
        if (j == 0) { p0 = v0.y; p1 = v1.y; }            // reflect col -1 -> 1
        else        { p0 = xp[r0 * W_IN + 4 * j - 1];    // wave seam (L1 hit)
                      p1 = xp[r1 * W_IN + 4 * j - 1]; }
    }

    float F[16];
#pragma unroll
    for (int k = 0; k < 16; ++k) F[k] = filt[k];

    const int bb = bc >> 5, cc = bc & 31;
    const long long obase = (long long)(bb * 128 + cc) * PLANE_OUT
                          + (long long)i * W_OUT;

#pragma unroll
    for (int k = 0; k < 4; ++k) {
        // out col 2j:   window (p0,   v0.x, p1,   v1.x)
        // out col 2j+1: window (v0.y, v0.z, v1.y, v1.z)
        float o0 = F[4*k+0]*p0   + F[4*k+1]*v0.x + F[4*k+2]*p1   + F[4*k+3]*v1.x;
        float o1 = F[4*k+0]*v0.y + F[4*k+1]*v0.z + F[4*k+2]*v1.y + F[4*k+3]*v1.z;
        f2v o; o.x = o0; o.y = o1;
        __builtin_nontemporal_store(
            o, reinterpret_cast<f2v*>(&out[obase + (long long)(k * 32) * PLANE_OUT + 2 * j]));
    }
    if (j == 127) {   // col tail j0=256: c0 = col 511 = v.w, c1 = 512 -> 510 = v.z
#pragma unroll
        for (int k = 0; k < 4; ++k) {
            float o = F[4*k+0]*v0.w + F[4*k+1]*v0.z + F[4*k+2]*v1.w + F[4*k+3]*v1.z;
            __builtin_nontemporal_store(
                o, &out[obase + (long long)(k * 32) * PLANE_OUT + 256]);
        }
    }
}

extern "C" void kernel_launch(void* const* d_in, const int* in_sizes, int n_in,
                              void* d_out, int out_size, void* d_ws, size_t ws_size,
                              hipStream_t stream) {
    const float* x    = (const float*)d_in[0];
    const float* filt = (const float*)d_in[1];
    float*       out  = (float*)d_out;

    dim3 grid((H_OUT + 1) / 2, 256);   // 129 row-pairs x 256 planes
    dwt2d_haar_reg<<<grid, 256, 0, stream>>>(x, filt, out);
}

// Round 5
// 94.951 us; speedup vs baseline: 1.1778x; 1.0562x over previous
//
#include <hip/hip_runtime.h>

// Haar DWT2D forward: (8,32,512,512) f32 -> (8,128,257,257) f32
// out[b, k*32+c, i, jo] uses input rows {2i-1, 2i}, cols {2jo-1, 2jo},
// reflect-1 padding (-1 -> 1, 512 -> 510).
//
// No LDS, no barriers, no shuffles. Lane j does a 4B-misaligned float4 load
// per input row (cols 4j-1 .. 4j+2), which self-contains both of its output
// windows (cols 2j and 2j+1). j==0 reflect handled by branchless selects.
// Each block = 4 consecutive output rows of one plane (2 sets x 128 lanes);
// all 4 row-pair loads issue up-front (MLP), and per-subband stores cover 4
// contiguous rows so row-boundary partial lines merge in L2.

constexpr int H_IN  = 512;
constexpr int W_IN  = 512;
constexpr int H_OUT = 257;
constexpr int W_OUT = 257;
constexpr int PLANE_OUT = H_OUT * W_OUT;   // 66049
constexpr int PLANE_IN  = H_IN * W_IN;     // 262144

typedef float f4v __attribute__((ext_vector_type(4), aligned(4)));
typedef float f2v __attribute__((ext_vector_type(2), aligned(4)));

__global__ __launch_bounds__(256)
void dwt2d_haar_r5(const float* __restrict__ x,
                   const float* __restrict__ filt,
                   float* __restrict__ out) {
    const int t  = threadIdx.x;
    const int j  = t & 127;          // output col-pair index
    const int s  = t >> 7;           // row set 0/1
    const int bc = blockIdx.y;       // b*32 + c
    const int i0 = blockIdx.x * 4;   // first output row of this block

    const int  iA = i0 + s;
    const int  iB = iA + 2;
    const bool vA = (iA < H_OUT);
    const bool vB = (iB < H_OUT);
    const int  iAc = vA ? iA : (H_OUT - 1);   // clamped for safe loads
    const int  iBc = vB ? iB : (H_OUT - 1);

    const float* xp = x + bc * PLANE_IN;
    const int  cb   = (j == 0) ? 0 : (4 * j - 1);  // misaligned col base
    const bool tail = (j == 127);

    int rA0 = 2 * iAc - 1; if (rA0 < 0)     rA0 = 1;
    int rA1 = 2 * iAc;     if (rA1 >= H_IN) rA1 = H_IN - 2;
    int rB0 = 2 * iBc - 1;
    int rB1 = 2 * iBc;     if (rB1 >= H_IN) rB1 = H_IN - 2;

    // tail lanes need col 511 of each input row (issued first, independent)
    float tA0 = 0.f, tA1 = 0.f, tB0 = 0.f, tB1 = 0.f;
    if (tail) {
        tA0 = xp[rA0 * W_IN + 511]; tA1 = xp[rA1 * W_IN + 511];
        tB0 = xp[rB0 * W_IN + 511]; tB1 = xp[rB1 * W_IN + 511];
    }

    // 4 independent (possibly misaligned) 16B loads, all in flight at once
    f4v vA0 = *reinterpret_cast<const f4v*>(xp + rA0 * W_IN + cb);
    f4v vA1 = *reinterpret_cast<const f4v*>(xp + rA1 * W_IN + cb);
    f4v vB0 = *reinterpret_cast<const f4v*>(xp + rB0 * W_IN + cb);
    f4v vB1 = *reinterpret_cast<const f4v*>(xp + rB1 * W_IN + cb);

    float F[16];
#pragma unroll
    for (int k = 0; k < 16; ++k) F[k] = filt[k];

    const int bb = bc >> 5, cc = bc & 31;
    const int pbase = (bb * 128 + cc) * PLANE_OUT;

    auto emit = [&](int i, const f4v& v0, const f4v& v1,
                    float t0, float t1, bool valid) {
        if (!valid) return;
        // even out col 2j: window cols {4j-1, 4j}; j==0 -> {reflect 1, 0}
        float a0 = j ? v0.x : v0.y,  b0 = j ? v0.y : v0.x;
        float a1 = j ? v1.x : v1.y,  b1 = j ? v1.y : v1.x;
        // odd out col 2j+1: window cols {4j+1, 4j+2}
        float c0 = j ? v0.z : v0.y,  d0 = j ? v0.w : v0.z;
        float c1 = j ? v1.z : v1.y,  d1 = j ? v1.w : v1.z;
        const int rbase = pbase + i * W_OUT;
#pragma unroll
        for (int k = 0; k < 4; ++k) {
            float oe = F[4*k]*a0 + F[4*k+1]*b0 + F[4*k+2]*a1 + F[4*k+3]*b1;
            float oo = F[4*k]*c0 + F[4*k+1]*d0 + F[4*k+2]*c1 + F[4*k+3]*d1;
            f2v o; o.x = oe; o.y = oo;
            __builtin_nontemporal_store(
                o, reinterpret_cast<f2v*>(&out[rbase + k * 32 * PLANE_OUT + 2 * j]));
            if (tail) {   // out col 256: window cols {511, 512 -> 510}
                float ot = F[4*k]*t0 + F[4*k+1]*v0.w + F[4*k+2]*t1 + F[4*k+3]*v1.w;
                __builtin_nontemporal_store(
                    ot, &out[rbase + k * 32 * PLANE_OUT + 256]);
            }
        }
    };

    emit(iA, vA0, vA1, tA0, tA1, vA);
    emit(iB, vB0, vB1, tB0, tB1, vB);
}

extern "C" void kernel_launch(void* const* d_in, const int* in_sizes, int n_in,
                              void* d_out, int out_size, void* d_ws, size_t ws_size,
                              hipStream_t stream) {
    const float* x    = (const float*)d_in[0];
    const float* filt = (const float*)d_in[1];
    float*       out  = (float*)d_out;

    dim3 grid((H_OUT + 3) / 4, 256);   // 65 row-groups x 256 planes
    dwt2d_haar_r5<<<grid, 256, 0, stream>>>(x, filt, out);
}